// Round 1
// baseline (276.016 us; speedup 1.0000x reference)
//
#include <hip/hip_runtime.h>
#include <hip/hip_cooperative_groups.h>
#include <hip/hip_bf16.h>
#include <stdint.h>

// SGPN similarity loss, fused: batched Gram (A·A^T, K=64) via bf16 MFMA +
// hinge epilogue + scalar mean reduction. B=4, C=64, N=4096, G=50.
//
// R3: persistent main kernel — 512 blocks (2/CU), double-buffered
//     global_load_lds staging, 4-5 tile-pairs per block.
// R4: single cooperative kernel — prep / main / reduce fused with two
//     grid.sync()s. Eliminates 2 kernel-launch overheads + inter-kernel
//     bubbles. All three phases are BIT-IDENTICAL in arithmetic and
//     reduction order to the R3 three-kernel version (prep runs on
//     blocks 0..255 with the original mapping; main schedule unchanged;
//     block 0 does the original reduce). Fallback to 3-kernel path if
//     cooperative launch is unavailable.
//
// ws layout: [0, 2MB)    gA : bf16 points, chunk-major tile images
//            [+2MB, 64K) gR : r[n] = sum_c f~^2 (fp32, from rounded vals)
//            [..,  +64K) gK : key (group id, or unique negative if -1)
//            [..,  +64K) gW : float(target)
//            [..,  +2K)  gP : per-block partials (512 floats)

#define NT 32                      // tiles per batch (4096/128)
#define TRI 528                    // NT*(NT+1)/2
#define NPAIR (4*TRI)              // 2112 tile-pairs
#define NBLK 512                   // persistent blocks (2/CU)
#define SCALE (1.0f/67108864.0f)   // 1/(B*N*N), exact power of two

typedef __attribute__((ext_vector_type(4))) float f32x4;
typedef __attribute__((ext_vector_type(8))) __bf16 bf16x8;

namespace cg = cooperative_groups;

__device__ __forceinline__ void async_load16(const void* g, void* l) {
    __builtin_amdgcn_global_load_lds(
        (const __attribute__((address_space(1))) uint32_t*)g,
        (__attribute__((address_space(3))) uint32_t*)l,
        16, 0, 0);
}

// ============================ fused cooperative kernel ============================
__global__ __launch_bounds__(256, 2) void sgpn_fused(
    const float* __restrict__ Fsim, const int* __restrict__ target,
    unsigned short* __restrict__ gA, float* __restrict__ gR,
    float* __restrict__ gK, float* __restrict__ gW,
    float* __restrict__ gP, float* __restrict__ out)
{
    // [buf][A=0/B=1][8192] bf16 chunk-major tile images : 64 KB
    __shared__ __align__(16) unsigned short lT[2][2][8192];
    // [buf][row=0/col=1][R=0,K=1,W=2][128] : 6 KB
    __shared__ __align__(16) float sM[2][2][3][128];
    __shared__ float sRed[4];
    __shared__ float sMult[2];
    __shared__ float sPart[4][64];   // prep-phase only (1 KB)

    int tid = threadIdx.x;
    int lane = tid & 63;
    int wave = tid >> 6;
    int g = blockIdx.x;

    // ---------------- phase 1: prep (blocks 0..255, original mapping) ----------------
    if (g < 256) {
        int b = g >> 6;
        int n0 = (g & 63) * 64;

        int n = n0 + lane;
        int gp = b * 4096 + n;
        const float* src = Fsim + (size_t)b * 64 * 4096 + n;
        int tile = n >> 7, row = n & 127;
        unsigned short* dst = gA + (size_t)(b * NT + tile) * 8192 + row * 8;

        float racc = 0.f;
        #pragma unroll
        for (int q = 0; q < 2; ++q) {
            int chunk = wave * 2 + q;
            unsigned us[8];
            #pragma unroll
            for (int j = 0; j < 8; ++j) {
                float f = src[(size_t)(chunk * 8 + j) * 4096];
                unsigned u = __float_as_uint(f);
                u += 0x7fffu + ((u >> 16) & 1u);    // RNE to bf16
                us[j] = u >> 16;
                float fb = __uint_as_float(us[j] << 16);
                racc = fmaf(fb, fb, racc);
            }
            uint4 pk;
            pk.x = us[0] | (us[1] << 16);
            pk.y = us[2] | (us[3] << 16);
            pk.z = us[4] | (us[5] << 16);
            pk.w = us[6] | (us[7] << 16);
            *(uint4*)(dst + chunk * 1024) = pk;
        }
        sPart[wave][lane] = racc;
        __syncthreads();
        if (wave == 0) {
            gR[gp] = (sPart[0][lane] + sPart[1][lane]) +
                     (sPart[2][lane] + sPart[3][lane]);
            int tg = target[gp];
            gK[gp] = (tg >= 0) ? (float)tg : -(float)(n + 2);  // unique key
            gW[gp] = (float)tg;
        }
    }
    __threadfence();
    cg::this_grid().sync();

    // ---------------- phase 2: main (all 512 blocks, original schedule) ----------------
    int np = (g < (NPAIR - 4 * NBLK)) ? 5 : 4;   // first 64 blocks take a 5th pair

    auto stage = [&](int P, int buf) {
        int b = P / TRI;
        int t = P - b * TRI;
        int tj = (int)((sqrtf(8.0f * (float)t + 1.0f) - 1.0f) * 0.5f);
        while ((tj + 1) * (tj + 2) / 2 <= t) ++tj;
        while (tj * (tj + 1) / 2 > t) --tj;
        int ti = t - tj * (tj + 1) / 2;

        const unsigned short* tA = gA + (size_t)(b * NT + ti) * 8192;
        const unsigned short* tB = gA + (size_t)(b * NT + tj) * 8192;
        #pragma unroll
        for (int it = 0; it < 4; ++it) {
            int e = it * 256 + tid;               // 16B chunk index
            async_load16(tA + e * 8, &lT[buf][0][e * 8]);
            async_load16(tB + e * 8, &lT[buf][1][e * 8]);
        }
        int half = tid >> 7, p0 = tid & 127;
        int gp = b * 4096 + (half ? tj : ti) * 128 + p0;
        sM[buf][half][0][p0] = gR[gp];
        sM[buf][half][1][p0] = gK[gp];
        sM[buf][half][2][p0] = gW[gp];
        if (tid == 0) sMult[buf] = (ti == tj) ? 1.f : 2.f;
    };

    int wr = wave >> 1, wc = wave & 1;
    int quad = lane >> 4, lcol = lane & 15;

    float total = 0.f;
    stage(g, 0);

    for (int q = 0; q < np; ++q) {
        __syncthreads();                       // drains staging of buf q&1
        int buf = q & 1;
        if (q + 1 < np) stage(g + (q + 1) * NBLK, buf ^ 1);  // async prefetch

        // ---- MFMA on buf ----
        f32x4 acc[4][4];
        #pragma unroll
        for (int i = 0; i < 4; ++i)
            #pragma unroll
            for (int j = 0; j < 4; ++j)
                acc[i][j] = (f32x4)0.f;

        #pragma unroll
        for (int kb = 0; kb < 2; ++kb) {
            int chunk = kb * 4 + quad;
            bf16x8 fa[4], fb[4];
            #pragma unroll
            for (int i = 0; i < 4; ++i)
                fa[i] = *(const bf16x8*)&lT[buf][0][chunk * 1024 + (wr * 64 + i * 16 + lcol) * 8];
            #pragma unroll
            for (int j = 0; j < 4; ++j)
                fb[j] = *(const bf16x8*)&lT[buf][1][chunk * 1024 + (wc * 64 + j * 16 + lcol) * 8];
            #pragma unroll
            for (int i = 0; i < 4; ++i)
                #pragma unroll
                for (int j = 0; j < 4; ++j)
                    acc[i][j] = __builtin_amdgcn_mfma_f32_16x16x32_bf16(fa[i], fb[j], acc[i][j], 0, 0, 0);
        }

        // ---- epilogue: C/D layout col = lane&15, row = quad*4 + reg ----
        float rcv[4], kcv[4], wcv[4];
        #pragma unroll
        for (int j = 0; j < 4; ++j) {
            int cl = wc * 64 + j * 16 + lcol;
            rcv[j] = sM[buf][1][0][cl];
            kcv[j] = sM[buf][1][1][cl];
            wcv[j] = sM[buf][1][2][cl];
        }

        float sum = 0.f;
        #pragma unroll
        for (int i = 0; i < 4; ++i) {
            int rb = wr * 64 + i * 16 + quad * 4;          // 4-aligned
            f32x4 rr4 = *(const f32x4*)&sM[buf][0][0][rb];
            f32x4 kr4 = *(const f32x4*)&sM[buf][0][1][rb];
            f32x4 wr4 = *(const f32x4*)&sM[buf][0][2][rb];
            #pragma unroll
            for (int r = 0; r < 4; ++r) {
                float rrow = rr4[r], krow = kr4[r], wrow = wr4[r];
                float psum = 0.f;
                #pragma unroll
                for (int j = 0; j < 4; ++j) {
                    float gacc = acc[i][j][r];
                    float d0 = fmaf(-2.f, gacc, rrow + rcv[j]);
                    float D  = fmaxf(d0, 0.f);
                    float h  = fmaxf(fmaf(D, -2.f, 1.6f), 0.f);   // 2*max(0.8-D,0)
                    float v  = (krow == kcv[j]) ? D : h;
                    psum = fmaf(v, wcv[j], psum);
                }
                sum = fmaf(psum, wrow, sum);
            }
        }
        total = fmaf(sum, sMult[buf], total);
    }

    // per-block reduce: wave shuffle -> LDS -> one store per block
    #pragma unroll
    for (int off = 32; off > 0; off >>= 1)
        total += __shfl_down(total, off, 64);
    if (lane == 0) sRed[wave] = total;
    __syncthreads();
    if (tid == 0)
        gP[g] = (sRed[0] + sRed[1]) + (sRed[2] + sRed[3]);

    __threadfence();
    cg::this_grid().sync();

    // ---------------- phase 3: reduce 512 partials -> scalar mean (block 0) ----------------
    if (g == 0) {
        float s = gP[tid] + gP[tid + 256];
        #pragma unroll
        for (int off = 32; off > 0; off >>= 1)
            s += __shfl_down(s, off, 64);
        if ((tid & 63) == 0) sRed[tid >> 6] = s;
        __syncthreads();
        if (tid == 0)
            out[0] = ((sRed[0] + sRed[1]) + (sRed[2] + sRed[3])) * SCALE;
    }
}

// ============================ fallback 3-kernel path ============================
__global__ __launch_bounds__(256) void sgpn_prep(
    const float* __restrict__ Fsim, const int* __restrict__ target,
    unsigned short* __restrict__ gA, float* __restrict__ gR,
    float* __restrict__ gK, float* __restrict__ gW)
{
    __shared__ float sPart[4][64];

    int blk = blockIdx.x;              // 0..255
    int b = blk >> 6;
    int n0 = (blk & 63) * 64;
    int lane = threadIdx.x & 63;
    int wave = threadIdx.x >> 6;

    int n = n0 + lane;
    int gp = b * 4096 + n;
    const float* src = Fsim + (size_t)b * 64 * 4096 + n;
    int tile = n >> 7, row = n & 127;
    unsigned short* dst = gA + (size_t)(b * NT + tile) * 8192 + row * 8;

    float racc = 0.f;
    #pragma unroll
    for (int q = 0; q < 2; ++q) {
        int chunk = wave * 2 + q;
        unsigned us[8];
        #pragma unroll
        for (int j = 0; j < 8; ++j) {
            float f = src[(size_t)(chunk * 8 + j) * 4096];
            unsigned u = __float_as_uint(f);
            u += 0x7fffu + ((u >> 16) & 1u);    // RNE to bf16
            us[j] = u >> 16;
            float fb = __uint_as_float(us[j] << 16);
            racc = fmaf(fb, fb, racc);
        }
        uint4 pk;
        pk.x = us[0] | (us[1] << 16);
        pk.y = us[2] | (us[3] << 16);
        pk.z = us[4] | (us[5] << 16);
        pk.w = us[6] | (us[7] << 16);
        *(uint4*)(dst + chunk * 1024) = pk;
    }
    sPart[wave][lane] = racc;
    __syncthreads();
    if (wave == 0) {
        gR[gp] = (sPart[0][lane] + sPart[1][lane]) +
                 (sPart[2][lane] + sPart[3][lane]);
        int tg = target[gp];
        gK[gp] = (tg >= 0) ? (float)tg : -(float)(n + 2);
        gW[gp] = (float)tg;
    }
}

__global__ __launch_bounds__(256, 2) void sgpn_main(
    const unsigned short* __restrict__ gA,
    const float* __restrict__ gR, const float* __restrict__ gK,
    const float* __restrict__ gW, float* __restrict__ gP)
{
    __shared__ __align__(16) unsigned short lT[2][2][8192];
    __shared__ __align__(16) float sM[2][2][3][128];
    __shared__ float sRed[4];
    __shared__ float sMult[2];

    int tid = threadIdx.x;
    int lane = tid & 63;
    int wave = tid >> 6;
    int g = blockIdx.x;
    int np = (g < (NPAIR - 4 * NBLK)) ? 5 : 4;

    auto stage = [&](int P, int buf) {
        int b = P / TRI;
        int t = P - b * TRI;
        int tj = (int)((sqrtf(8.0f * (float)t + 1.0f) - 1.0f) * 0.5f);
        while ((tj + 1) * (tj + 2) / 2 <= t) ++tj;
        while (tj * (tj + 1) / 2 > t) --tj;
        int ti = t - tj * (tj + 1) / 2;

        const unsigned short* tA = gA + (size_t)(b * NT + ti) * 8192;
        const unsigned short* tB = gA + (size_t)(b * NT + tj) * 8192;
        #pragma unroll
        for (int it = 0; it < 4; ++it) {
            int e = it * 256 + tid;
            async_load16(tA + e * 8, &lT[buf][0][e * 8]);
            async_load16(tB + e * 8, &lT[buf][1][e * 8]);
        }
        int half = tid >> 7, p0 = tid & 127;
        int gp = b * 4096 + (half ? tj : ti) * 128 + p0;
        sM[buf][half][0][p0] = gR[gp];
        sM[buf][half][1][p0] = gK[gp];
        sM[buf][half][2][p0] = gW[gp];
        if (tid == 0) sMult[buf] = (ti == tj) ? 1.f : 2.f;
    };

    int wr = wave >> 1, wc = wave & 1;
    int quad = lane >> 4, lcol = lane & 15;

    float total = 0.f;
    stage(g, 0);

    for (int q = 0; q < np; ++q) {
        __syncthreads();
        int buf = q & 1;
        if (q + 1 < np) stage(g + (q + 1) * NBLK, buf ^ 1);

        f32x4 acc[4][4];
        #pragma unroll
        for (int i = 0; i < 4; ++i)
            #pragma unroll
            for (int j = 0; j < 4; ++j)
                acc[i][j] = (f32x4)0.f;

        #pragma unroll
        for (int kb = 0; kb < 2; ++kb) {
            int chunk = kb * 4 + quad;
            bf16x8 fa[4], fb[4];
            #pragma unroll
            for (int i = 0; i < 4; ++i)
                fa[i] = *(const bf16x8*)&lT[buf][0][chunk * 1024 + (wr * 64 + i * 16 + lcol) * 8];
            #pragma unroll
            for (int j = 0; j < 4; ++j)
                fb[j] = *(const bf16x8*)&lT[buf][1][chunk * 1024 + (wc * 64 + j * 16 + lcol) * 8];
            #pragma unroll
            for (int i = 0; i < 4; ++i)
                #pragma unroll
                for (int j = 0; j < 4; ++j)
                    acc[i][j] = __builtin_amdgcn_mfma_f32_16x16x32_bf16(fa[i], fb[j], acc[i][j], 0, 0, 0);
        }

        float rcv[4], kcv[4], wcv[4];
        #pragma unroll
        for (int j = 0; j < 4; ++j) {
            int cl = wc * 64 + j * 16 + lcol;
            rcv[j] = sM[buf][1][0][cl];
            kcv[j] = sM[buf][1][1][cl];
            wcv[j] = sM[buf][1][2][cl];
        }

        float sum = 0.f;
        #pragma unroll
        for (int i = 0; i < 4; ++i) {
            int rb = wr * 64 + i * 16 + quad * 4;
            f32x4 rr4 = *(const f32x4*)&sM[buf][0][0][rb];
            f32x4 kr4 = *(const f32x4*)&sM[buf][0][1][rb];
            f32x4 wr4 = *(const f32x4*)&sM[buf][0][2][rb];
            #pragma unroll
            for (int r = 0; r < 4; ++r) {
                float rrow = rr4[r], krow = kr4[r], wrow = wr4[r];
                float psum = 0.f;
                #pragma unroll
                for (int j = 0; j < 4; ++j) {
                    float gacc = acc[i][j][r];
                    float d0 = fmaf(-2.f, gacc, rrow + rcv[j]);
                    float D  = fmaxf(d0, 0.f);
                    float h  = fmaxf(fmaf(D, -2.f, 1.6f), 0.f);
                    float v  = (krow == kcv[j]) ? D : h;
                    psum = fmaf(v, wcv[j], psum);
                }
                sum = fmaf(psum, wrow, sum);
            }
        }
        total = fmaf(sum, sMult[buf], total);
    }

    #pragma unroll
    for (int off = 32; off > 0; off >>= 1)
        total += __shfl_down(total, off, 64);
    if (lane == 0) sRed[wave] = total;
    __syncthreads();
    if (tid == 0)
        gP[g] = (sRed[0] + sRed[1]) + (sRed[2] + sRed[3]);
}

__global__ __launch_bounds__(256) void sgpn_reduce(
    const float* __restrict__ gP, float* __restrict__ out)
{
    __shared__ float sr[4];
    int tid = threadIdx.x;
    float s = gP[tid] + gP[tid + 256];
    #pragma unroll
    for (int off = 32; off > 0; off >>= 1)
        s += __shfl_down(s, off, 64);
    if ((tid & 63) == 0) sr[tid >> 6] = s;
    __syncthreads();
    if (tid == 0)
        out[0] = ((sr[0] + sr[1]) + (sr[2] + sr[3])) * SCALE;
}

extern "C" void kernel_launch(void* const* d_in, const int* in_sizes, int n_in,
                              void* d_out, int out_size, void* d_ws, size_t ws_size,
                              hipStream_t stream) {
    // d_in: [0]=l0_points (unused), [1]=Fsim fp32 [4,64,4096], [2]=target int32 [4,4096]
    const float* Fsim  = (const float*)d_in[1];
    const int* target  = (const int*)d_in[2];
    float* out = (float*)d_out;

    char* ws = (char*)d_ws;
    unsigned short* gA = (unsigned short*)ws;                 // 2 MB
    float* gR = (float*)(ws + (2u << 20));                    // 64 KB
    float* gK = (float*)(ws + (2u << 20) + (64u << 10));      // 64 KB
    float* gW = (float*)(ws + (2u << 20) + (128u << 10));     // 64 KB
    float* gP = (float*)(ws + (2u << 20) + (192u << 10));     // 2 KB

    void* args[] = {(void*)&Fsim, (void*)&target, (void*)&gA, (void*)&gR,
                    (void*)&gK, (void*)&gW, (void*)&gP, (void*)&out};
    hipError_t err = hipLaunchCooperativeKernel(
        (const void*)sgpn_fused, dim3(NBLK), dim3(256), args, 0, stream);

    if (err != hipSuccess) {
        // fallback: original 3-kernel path (bit-identical result)
        sgpn_prep<<<256, 256, 0, stream>>>(Fsim, target, gA, gR, gK, gW);
        sgpn_main<<<NBLK, 256, 0, stream>>>(gA, gR, gK, gW, gP);
        sgpn_reduce<<<1, 256, 0, stream>>>(gP, out);
    }
}

// Round 2
// 83.642 us; speedup vs baseline: 3.3000x; 3.3000x over previous
//
#include <hip/hip_runtime.h>
#include <hip/hip_bf16.h>
#include <stdint.h>

// SGPN similarity loss, fused: batched Gram (A·A^T, K=64) via bf16 MFMA +
// hinge epilogue + scalar mean reduction. B=4, C=64, N=4096, G=50.
//
// R3: persistent main kernel — 512 blocks (2/CU, 73 KB LDS), double-buffered
//     global_load_lds staging, 4-5 tile-pairs per block.   [77.3 us]
// R4: cooperative-fused — REGRESSED to 276 us: cg::grid.sync() spin-poll
//     across 512 blocks cost ~170 us. Reverted.
// R5: 3-phase -> 2 launches: final reduce merged into main via
//     last-block-done atomic (one atomicAdd per block, NO spinning).
//     All arithmetic / reduction orders bit-identical to R3.
//
// ws layout: [0, 2MB)    gA : bf16 points, chunk-major tile images
//            [+2MB, 64K) gR : r[n] = sum_c f~^2 (fp32, from rounded vals)
//            [..,  +64K) gK : key (group id, or unique negative if -1)
//            [..,  +64K) gW : float(target)
//            [..,  +2K)  gP : per-block partials (512 floats)
//            [..,  +4B)  gC : completion counter (zeroed by prep)

#define NT 32                      // tiles per batch (4096/128)
#define TRI 528                    // NT*(NT+1)/2
#define NPAIR (4*TRI)              // 2112 tile-pairs
#define NBLK 512                   // persistent main blocks (2/CU)
#define SCALE (1.0f/67108864.0f)   // 1/(B*N*N), exact power of two

typedef __attribute__((ext_vector_type(4))) float f32x4;
typedef __attribute__((ext_vector_type(8))) __bf16 bf16x8;

__device__ __forceinline__ void async_load16(const void* g, void* l) {
    __builtin_amdgcn_global_load_lds(
        (const __attribute__((address_space(1))) uint32_t*)g,
        (__attribute__((address_space(3))) uint32_t*)l,
        16, 0, 0);
}

// ---------------- prep: transpose+cast Fsim, compute r/key/w ----------------
// block = 64 points; wave w handles channels [w*16, w*16+16) for all 64 points.
__global__ __launch_bounds__(256) void sgpn_prep(
    const float* __restrict__ Fsim, const int* __restrict__ target,
    unsigned short* __restrict__ gA, float* __restrict__ gR,
    float* __restrict__ gK, float* __restrict__ gW,
    unsigned* __restrict__ gC)
{
    __shared__ float sPart[4][64];

    int blk = blockIdx.x;              // 0..255
    if (blk == 0 && threadIdx.x == 0) *gC = 0u;   // reset last-block counter
    int b = blk >> 6;
    int n0 = (blk & 63) * 64;
    int lane = threadIdx.x & 63;
    int wave = threadIdx.x >> 6;

    int n = n0 + lane;
    int gp = b * 4096 + n;
    const float* src = Fsim + (size_t)b * 64 * 4096 + n;
    int tile = n >> 7, row = n & 127;
    unsigned short* dst = gA + (size_t)(b * NT + tile) * 8192 + row * 8;

    float racc = 0.f;
    #pragma unroll
    for (int q = 0; q < 2; ++q) {
        int chunk = wave * 2 + q;
        unsigned us[8];
        #pragma unroll
        for (int j = 0; j < 8; ++j) {
            float f = src[(size_t)(chunk * 8 + j) * 4096];
            unsigned u = __float_as_uint(f);
            u += 0x7fffu + ((u >> 16) & 1u);    // RNE to bf16
            us[j] = u >> 16;
            float fb = __uint_as_float(us[j] << 16);
            racc = fmaf(fb, fb, racc);
        }
        uint4 pk;
        pk.x = us[0] | (us[1] << 16);
        pk.y = us[2] | (us[3] << 16);
        pk.z = us[4] | (us[5] << 16);
        pk.w = us[6] | (us[7] << 16);
        *(uint4*)(dst + chunk * 1024) = pk;
    }
    sPart[wave][lane] = racc;
    __syncthreads();
    if (wave == 0) {
        gR[gp] = (sPart[0][lane] + sPart[1][lane]) +
                 (sPart[2][lane] + sPart[3][lane]);
        int tg = target[gp];
        gK[gp] = (tg >= 0) ? (float)tg : -(float)(n + 2);  // unique key
        gW[gp] = (float)tg;
    }
}

// ---------------- main: persistent, dbuf-staged 128x128 tile-pairs ----------------
// + merged final reduce: last block to finish reduces the 512 partials.
__global__ __launch_bounds__(256, 2) void sgpn_main(
    const unsigned short* __restrict__ gA,
    const float* __restrict__ gR, const float* __restrict__ gK,
    const float* __restrict__ gW, float* __restrict__ gP,
    unsigned* __restrict__ gC, float* __restrict__ out)
{
    // [buf][A=0/B=1][8192] bf16 chunk-major tile images : 64 KB
    __shared__ __align__(16) unsigned short lT[2][2][8192];
    // [buf][row=0/col=1][R=0,K=1,W=2][128] : 6 KB
    __shared__ __align__(16) float sM[2][2][3][128];
    __shared__ float sRed[4];
    __shared__ float sMult[2];
    __shared__ unsigned sLast;

    int tid = threadIdx.x;
    int lane = tid & 63;
    int wave = tid >> 6;
    int g = blockIdx.x;
    int np = (g < (NPAIR - 4 * NBLK)) ? 5 : 4;   // first 64 blocks take a 5th pair

    auto stage = [&](int P, int buf) {
        int b = P / TRI;
        int t = P - b * TRI;
        int tj = (int)((sqrtf(8.0f * (float)t + 1.0f) - 1.0f) * 0.5f);
        while ((tj + 1) * (tj + 2) / 2 <= t) ++tj;
        while (tj * (tj + 1) / 2 > t) --tj;
        int ti = t - tj * (tj + 1) / 2;

        const unsigned short* tA = gA + (size_t)(b * NT + ti) * 8192;
        const unsigned short* tB = gA + (size_t)(b * NT + tj) * 8192;
        #pragma unroll
        for (int it = 0; it < 4; ++it) {
            int e = it * 256 + tid;               // 16B chunk index
            async_load16(tA + e * 8, &lT[buf][0][e * 8]);
            async_load16(tB + e * 8, &lT[buf][1][e * 8]);
        }
        int half = tid >> 7, p0 = tid & 127;
        int gp = b * 4096 + (half ? tj : ti) * 128 + p0;
        sM[buf][half][0][p0] = gR[gp];
        sM[buf][half][1][p0] = gK[gp];
        sM[buf][half][2][p0] = gW[gp];
        if (tid == 0) sMult[buf] = (ti == tj) ? 1.f : 2.f;
    };

    int wr = wave >> 1, wc = wave & 1;
    int quad = lane >> 4, lcol = lane & 15;

    float total = 0.f;
    stage(g, 0);

    for (int q = 0; q < np; ++q) {
        __syncthreads();                       // drains staging of buf q&1
        int buf = q & 1;
        if (q + 1 < np) stage(g + (q + 1) * NBLK, buf ^ 1);  // async prefetch

        // ---- MFMA on buf ----
        f32x4 acc[4][4];
        #pragma unroll
        for (int i = 0; i < 4; ++i)
            #pragma unroll
            for (int j = 0; j < 4; ++j)
                acc[i][j] = (f32x4)0.f;

        #pragma unroll
        for (int kb = 0; kb < 2; ++kb) {
            int chunk = kb * 4 + quad;
            bf16x8 fa[4], fb[4];
            #pragma unroll
            for (int i = 0; i < 4; ++i)
                fa[i] = *(const bf16x8*)&lT[buf][0][chunk * 1024 + (wr * 64 + i * 16 + lcol) * 8];
            #pragma unroll
            for (int j = 0; j < 4; ++j)
                fb[j] = *(const bf16x8*)&lT[buf][1][chunk * 1024 + (wc * 64 + j * 16 + lcol) * 8];
            #pragma unroll
            for (int i = 0; i < 4; ++i)
                #pragma unroll
                for (int j = 0; j < 4; ++j)
                    acc[i][j] = __builtin_amdgcn_mfma_f32_16x16x32_bf16(fa[i], fb[j], acc[i][j], 0, 0, 0);
        }

        // ---- epilogue: C/D layout col = lane&15, row = quad*4 + reg ----
        float rcv[4], kcv[4], wcv[4];
        #pragma unroll
        for (int j = 0; j < 4; ++j) {
            int cl = wc * 64 + j * 16 + lcol;
            rcv[j] = sM[buf][1][0][cl];
            kcv[j] = sM[buf][1][1][cl];
            wcv[j] = sM[buf][1][2][cl];
        }

        float sum = 0.f;
        #pragma unroll
        for (int i = 0; i < 4; ++i) {
            int rb = wr * 64 + i * 16 + quad * 4;          // 4-aligned
            f32x4 rr4 = *(const f32x4*)&sM[buf][0][0][rb];
            f32x4 kr4 = *(const f32x4*)&sM[buf][0][1][rb];
            f32x4 wr4 = *(const f32x4*)&sM[buf][0][2][rb];
            #pragma unroll
            for (int r = 0; r < 4; ++r) {
                float rrow = rr4[r], krow = kr4[r], wrow = wr4[r];
                float psum = 0.f;
                #pragma unroll
                for (int j = 0; j < 4; ++j) {
                    float gacc = acc[i][j][r];
                    float d0 = fmaf(-2.f, gacc, rrow + rcv[j]);
                    float D  = fmaxf(d0, 0.f);
                    float h  = fmaxf(fmaf(D, -2.f, 1.6f), 0.f);   // 2*max(0.8-D,0)
                    float v  = (krow == kcv[j]) ? D : h;
                    psum = fmaf(v, wcv[j], psum);
                }
                sum = fmaf(psum, wrow, sum);
            }
        }
        total = fmaf(sum, sMult[buf], total);
    }

    // per-block reduce: wave shuffle -> LDS -> one store per block
    #pragma unroll
    for (int off = 32; off > 0; off >>= 1)
        total += __shfl_down(total, off, 64);
    if (lane == 0) sRed[wave] = total;
    __syncthreads();
    if (tid == 0) {
        gP[g] = (sRed[0] + sRed[1]) + (sRed[2] + sRed[3]);
        __threadfence();                               // release gP[g]
        sLast = (atomicAdd(gC, 1u) == NBLK - 1u) ? 1u : 0u;
    }
    __syncthreads();

    // ---- last block to arrive reduces the 512 partials (no spinning) ----
    if (sLast) {
        __threadfence();                               // acquire all gP
        float s = gP[tid] + gP[tid + 256];
        #pragma unroll
        for (int off = 32; off > 0; off >>= 1)
            s += __shfl_down(s, off, 64);
        if ((tid & 63) == 0) sRed[tid >> 6] = s;
        __syncthreads();
        if (tid == 0)
            out[0] = ((sRed[0] + sRed[1]) + (sRed[2] + sRed[3])) * SCALE;
    }
}

extern "C" void kernel_launch(void* const* d_in, const int* in_sizes, int n_in,
                              void* d_out, int out_size, void* d_ws, size_t ws_size,
                              hipStream_t stream) {
    // d_in: [0]=l0_points (unused), [1]=Fsim fp32 [4,64,4096], [2]=target int32 [4,4096]
    const float* Fsim  = (const float*)d_in[1];
    const int* target  = (const int*)d_in[2];
    float* out = (float*)d_out;

    char* ws = (char*)d_ws;
    unsigned short* gA = (unsigned short*)ws;                 // 2 MB
    float* gR = (float*)(ws + (2u << 20));                    // 64 KB
    float* gK = (float*)(ws + (2u << 20) + (64u << 10));      // 64 KB
    float* gW = (float*)(ws + (2u << 20) + (128u << 10));     // 64 KB
    float* gP = (float*)(ws + (2u << 20) + (192u << 10));     // 2 KB
    unsigned* gC = (unsigned*)(ws + (2u << 20) + (194u << 10)); // 4 B

    sgpn_prep<<<256, 256, 0, stream>>>(Fsim, target, gA, gR, gK, gW, gC);
    sgpn_main<<<NBLK, 256, 0, stream>>>(gA, gR, gK, gW, gP, gC, out);
}

// Round 3
// 79.770 us; speedup vs baseline: 3.4601x; 1.0485x over previous
//
#include <hip/hip_runtime.h>
#include <hip/hip_bf16.h>
#include <stdint.h>

// SGPN similarity loss, fused: batched Gram (A·A^T, K=64) via bf16 MFMA +
// hinge epilogue + scalar mean reduction. B=4, C=64, N=4096, G=50.
//
// R3: persistent main kernel — 512 blocks (2/CU, 73 KB LDS), double-buffered
//     global_load_lds staging, 4-5 tile-pairs per block.   [77.3 us]
// R4: cooperative-fused — REGRESSED (276 us): cg::grid.sync() spin-poll.
// R5: reduce merged via plain-store + __threadfence() + atomic counter —
//     REGRESSED (83.6 us): device-scope threadfence = L2 writeback per block.
// R6: reduce merged FENCE-FREE: partial published via atomicExch (device-
//     coherent, no L2 flush), ordered before the counter bump by a single
//     s_waitcnt vmcnt(0); last block reads partials via atomic loads.
//     gP values and final summation order byte-identical to R3's reduce.
//
// ws layout: [0, 2MB)    gA : bf16 points, chunk-major tile images
//            [+2MB, 64K) gR : r[n] = sum_c f~^2 (fp32, from rounded vals)
//            [..,  +64K) gK : key (group id, or unique negative if -1)
//            [..,  +64K) gW : float(target)
//            [..,  +2K)  gP : per-block partials (512 floats)
//            [..,  +4B)  gC : completion counter (zeroed by prep)

#define NT 32                      // tiles per batch (4096/128)
#define TRI 528                    // NT*(NT+1)/2
#define NPAIR (4*TRI)              // 2112 tile-pairs
#define NBLK 512                   // persistent main blocks (2/CU)
#define SCALE (1.0f/67108864.0f)   // 1/(B*N*N), exact power of two

typedef __attribute__((ext_vector_type(4))) float f32x4;
typedef __attribute__((ext_vector_type(8))) __bf16 bf16x8;

__device__ __forceinline__ void async_load16(const void* g, void* l) {
    __builtin_amdgcn_global_load_lds(
        (const __attribute__((address_space(1))) uint32_t*)g,
        (__attribute__((address_space(3))) uint32_t*)l,
        16, 0, 0);
}

// ---------------- prep: transpose+cast Fsim, compute r/key/w ----------------
// block = 64 points; wave w handles channels [w*16, w*16+16) for all 64 points.
__global__ __launch_bounds__(256) void sgpn_prep(
    const float* __restrict__ Fsim, const int* __restrict__ target,
    unsigned short* __restrict__ gA, float* __restrict__ gR,
    float* __restrict__ gK, float* __restrict__ gW,
    unsigned* __restrict__ gC)
{
    __shared__ float sPart[4][64];

    int blk = blockIdx.x;              // 0..255
    if (blk == 0 && threadIdx.x == 0) *gC = 0u;   // reset last-block counter
    int b = blk >> 6;
    int n0 = (blk & 63) * 64;
    int lane = threadIdx.x & 63;
    int wave = threadIdx.x >> 6;

    int n = n0 + lane;
    int gp = b * 4096 + n;
    const float* src = Fsim + (size_t)b * 64 * 4096 + n;
    int tile = n >> 7, row = n & 127;
    unsigned short* dst = gA + (size_t)(b * NT + tile) * 8192 + row * 8;

    float racc = 0.f;
    #pragma unroll
    for (int q = 0; q < 2; ++q) {
        int chunk = wave * 2 + q;
        unsigned us[8];
        #pragma unroll
        for (int j = 0; j < 8; ++j) {
            float f = src[(size_t)(chunk * 8 + j) * 4096];
            unsigned u = __float_as_uint(f);
            u += 0x7fffu + ((u >> 16) & 1u);    // RNE to bf16
            us[j] = u >> 16;
            float fb = __uint_as_float(us[j] << 16);
            racc = fmaf(fb, fb, racc);
        }
        uint4 pk;
        pk.x = us[0] | (us[1] << 16);
        pk.y = us[2] | (us[3] << 16);
        pk.z = us[4] | (us[5] << 16);
        pk.w = us[6] | (us[7] << 16);
        *(uint4*)(dst + chunk * 1024) = pk;
    }
    sPart[wave][lane] = racc;
    __syncthreads();
    if (wave == 0) {
        gR[gp] = (sPart[0][lane] + sPart[1][lane]) +
                 (sPart[2][lane] + sPart[3][lane]);
        int tg = target[gp];
        gK[gp] = (tg >= 0) ? (float)tg : -(float)(n + 2);  // unique key
        gW[gp] = (float)tg;
    }
}

// ---------------- main: persistent, dbuf-staged 128x128 tile-pairs ----------------
// + merged final reduce: last block to arrive reduces the 512 partials.
//   All cross-block data flows through device-coherent atomics — no fences.
__global__ __launch_bounds__(256, 2) void sgpn_main(
    const unsigned short* __restrict__ gA,
    const float* __restrict__ gR, const float* __restrict__ gK,
    const float* __restrict__ gW, float* gP,
    unsigned* gC, float* __restrict__ out)
{
    // [buf][A=0/B=1][8192] bf16 chunk-major tile images : 64 KB
    __shared__ __align__(16) unsigned short lT[2][2][8192];
    // [buf][row=0/col=1][R=0,K=1,W=2][128] : 6 KB
    __shared__ __align__(16) float sM[2][2][3][128];
    __shared__ float sRed[4];
    __shared__ float sMult[2];
    __shared__ unsigned sLast;

    int tid = threadIdx.x;
    int lane = tid & 63;
    int wave = tid >> 6;
    int g = blockIdx.x;
    int np = (g < (NPAIR - 4 * NBLK)) ? 5 : 4;   // first 64 blocks take a 5th pair

    auto stage = [&](int P, int buf) {
        int b = P / TRI;
        int t = P - b * TRI;
        int tj = (int)((sqrtf(8.0f * (float)t + 1.0f) - 1.0f) * 0.5f);
        while ((tj + 1) * (tj + 2) / 2 <= t) ++tj;
        while (tj * (tj + 1) / 2 > t) --tj;
        int ti = t - tj * (tj + 1) / 2;

        const unsigned short* tA = gA + (size_t)(b * NT + ti) * 8192;
        const unsigned short* tB = gA + (size_t)(b * NT + tj) * 8192;
        #pragma unroll
        for (int it = 0; it < 4; ++it) {
            int e = it * 256 + tid;               // 16B chunk index
            async_load16(tA + e * 8, &lT[buf][0][e * 8]);
            async_load16(tB + e * 8, &lT[buf][1][e * 8]);
        }
        int half = tid >> 7, p0 = tid & 127;
        int gp = b * 4096 + (half ? tj : ti) * 128 + p0;
        sM[buf][half][0][p0] = gR[gp];
        sM[buf][half][1][p0] = gK[gp];
        sM[buf][half][2][p0] = gW[gp];
        if (tid == 0) sMult[buf] = (ti == tj) ? 1.f : 2.f;
    };

    int wr = wave >> 1, wc = wave & 1;
    int quad = lane >> 4, lcol = lane & 15;

    float total = 0.f;
    stage(g, 0);

    for (int q = 0; q < np; ++q) {
        __syncthreads();                       // drains staging of buf q&1
        int buf = q & 1;
        if (q + 1 < np) stage(g + (q + 1) * NBLK, buf ^ 1);  // async prefetch

        // ---- MFMA on buf ----
        f32x4 acc[4][4];
        #pragma unroll
        for (int i = 0; i < 4; ++i)
            #pragma unroll
            for (int j = 0; j < 4; ++j)
                acc[i][j] = (f32x4)0.f;

        #pragma unroll
        for (int kb = 0; kb < 2; ++kb) {
            int chunk = kb * 4 + quad;
            bf16x8 fa[4], fb[4];
            #pragma unroll
            for (int i = 0; i < 4; ++i)
                fa[i] = *(const bf16x8*)&lT[buf][0][chunk * 1024 + (wr * 64 + i * 16 + lcol) * 8];
            #pragma unroll
            for (int j = 0; j < 4; ++j)
                fb[j] = *(const bf16x8*)&lT[buf][1][chunk * 1024 + (wc * 64 + j * 16 + lcol) * 8];
            #pragma unroll
            for (int i = 0; i < 4; ++i)
                #pragma unroll
                for (int j = 0; j < 4; ++j)
                    acc[i][j] = __builtin_amdgcn_mfma_f32_16x16x32_bf16(fa[i], fb[j], acc[i][j], 0, 0, 0);
        }

        // ---- epilogue: C/D layout col = lane&15, row = quad*4 + reg ----
        float rcv[4], kcv[4], wcv[4];
        #pragma unroll
        for (int j = 0; j < 4; ++j) {
            int cl = wc * 64 + j * 16 + lcol;
            rcv[j] = sM[buf][1][0][cl];
            kcv[j] = sM[buf][1][1][cl];
            wcv[j] = sM[buf][1][2][cl];
        }

        float sum = 0.f;
        #pragma unroll
        for (int i = 0; i < 4; ++i) {
            int rb = wr * 64 + i * 16 + quad * 4;          // 4-aligned
            f32x4 rr4 = *(const f32x4*)&sM[buf][0][0][rb];
            f32x4 kr4 = *(const f32x4*)&sM[buf][0][1][rb];
            f32x4 wr4 = *(const f32x4*)&sM[buf][0][2][rb];
            #pragma unroll
            for (int r = 0; r < 4; ++r) {
                float rrow = rr4[r], krow = kr4[r], wrow = wr4[r];
                float psum = 0.f;
                #pragma unroll
                for (int j = 0; j < 4; ++j) {
                    float gacc = acc[i][j][r];
                    float d0 = fmaf(-2.f, gacc, rrow + rcv[j]);
                    float D  = fmaxf(d0, 0.f);
                    float h  = fmaxf(fmaf(D, -2.f, 1.6f), 0.f);   // 2*max(0.8-D,0)
                    float v  = (krow == kcv[j]) ? D : h;
                    psum = fmaf(v, wcv[j], psum);
                }
                sum = fmaf(psum, wrow, sum);
            }
        }
        total = fmaf(sum, sMult[buf], total);
    }

    // per-block reduce: wave shuffle -> LDS -> publish via coherent atomic
    #pragma unroll
    for (int off = 32; off > 0; off >>= 1)
        total += __shfl_down(total, off, 64);
    if (lane == 0) sRed[wave] = total;
    __syncthreads();
    if (tid == 0) {
        float pb = (sRed[0] + sRed[1]) + (sRed[2] + sRed[3]);
        atomicExch(&gP[g], pb);                        // device-coherent publish
        asm volatile("s_waitcnt vmcnt(0)" ::: "memory");  // exch reached LLC
        sLast = (atomicAdd(gC, 1u) == NBLK - 1u) ? 1u : 0u;
    }
    __syncthreads();

    // ---- last block to arrive reduces the 512 partials (coherent atomic reads) ----
    if (sLast) {
        float a = atomicAdd(&gP[tid], 0.0f);           // returns published value
        float b = atomicAdd(&gP[tid + 256], 0.0f);
        float s = a + b;
        #pragma unroll
        for (int off = 32; off > 0; off >>= 1)
            s += __shfl_down(s, off, 64);
        if ((tid & 63) == 0) sRed[tid >> 6] = s;
        __syncthreads();
        if (tid == 0)
            out[0] = ((sRed[0] + sRed[1]) + (sRed[2] + sRed[3])) * SCALE;
    }
}

extern "C" void kernel_launch(void* const* d_in, const int* in_sizes, int n_in,
                              void* d_out, int out_size, void* d_ws, size_t ws_size,
                              hipStream_t stream) {
    // d_in: [0]=l0_points (unused), [1]=Fsim fp32 [4,64,4096], [2]=target int32 [4,4096]
    const float* Fsim  = (const float*)d_in[1];
    const int* target  = (const int*)d_in[2];
    float* out = (float*)d_out;

    char* ws = (char*)d_ws;
    unsigned short* gA = (unsigned short*)ws;                 // 2 MB
    float* gR = (float*)(ws + (2u << 20));                    // 64 KB
    float* gK = (float*)(ws + (2u << 20) + (64u << 10));      // 64 KB
    float* gW = (float*)(ws + (2u << 20) + (128u << 10));     // 64 KB
    float* gP = (float*)(ws + (2u << 20) + (192u << 10));     // 2 KB
    unsigned* gC = (unsigned*)(ws + (2u << 20) + (194u << 10)); // 4 B

    sgpn_prep<<<256, 256, 0, stream>>>(Fsim, target, gA, gR, gK, gW, gC);
    sgpn_main<<<NBLK, 256, 0, stream>>>(gA, gR, gK, gW, gP, gC, out);
}

// Round 4
// 76.730 us; speedup vs baseline: 3.5972x; 1.0396x over previous
//
#include <hip/hip_runtime.h>
#include <hip/hip_bf16.h>
#include <stdint.h>

// SGPN similarity loss, fused: batched Gram (A·A^T, K=64) via bf16 MFMA +
// hinge epilogue + scalar mean reduction. B=4, C=64, N=4096, G=50.
//
// R3: persistent main — 512 blocks x 256 thr (2/CU, 73 KB LDS), dbuf
//     global_load_lds staging, 4-5 tile-pairs/block.        [77.3 us]
// R4: cooperative-fused — REGRESSED (276 us): grid.sync spin-poll.
// R5: tail merged w/ threadfence — REGRESSED (83.6): L2 writeback/block.
// R6: tail merged w/ coherent atomics — neutral-to-worse (79.8, noise).
//     Conclusion: launch-boundary cost ~0-2 us. Reverted to 3-kernel.
// R7: occupancy attack — main blocks 256->512 threads (8 waves), same
//     2 blocks/CU and same LDS: waves/SIMD 2->4. Each wave owns 64x32
//     outputs (acc[4][2]); staging/LDS layout/pair schedule unchanged.
//
// ws layout: [0, 2MB)    gA : bf16 points, chunk-major tile images
//            [+2MB, 64K) gR : r[n] = sum_c f~^2 (fp32, from rounded vals)
//            [..,  +64K) gK : key (group id, or unique negative if -1)
//            [..,  +64K) gW : float(target)
//            [..,  +2K)  gP : per-block partials (512 floats)

#define NT 32                      // tiles per batch (4096/128)
#define TRI 528                    // NT*(NT+1)/2
#define NPAIR (4*TRI)              // 2112 tile-pairs
#define NBLK 512                   // persistent main blocks (2/CU)
#define SCALE (1.0f/67108864.0f)   // 1/(B*N*N), exact power of two

typedef __attribute__((ext_vector_type(4))) float f32x4;
typedef __attribute__((ext_vector_type(8))) __bf16 bf16x8;

__device__ __forceinline__ void async_load16(const void* g, void* l) {
    __builtin_amdgcn_global_load_lds(
        (const __attribute__((address_space(1))) uint32_t*)g,
        (__attribute__((address_space(3))) uint32_t*)l,
        16, 0, 0);
}

// ---------------- prep: transpose+cast Fsim, compute r/key/w ----------------
// block = 64 points; wave w handles channels [w*16, w*16+16) for all 64 points.
__global__ __launch_bounds__(256) void sgpn_prep(
    const float* __restrict__ Fsim, const int* __restrict__ target,
    unsigned short* __restrict__ gA, float* __restrict__ gR,
    float* __restrict__ gK, float* __restrict__ gW)
{
    __shared__ float sPart[4][64];

    int blk = blockIdx.x;              // 0..255
    int b = blk >> 6;
    int n0 = (blk & 63) * 64;
    int lane = threadIdx.x & 63;
    int wave = threadIdx.x >> 6;

    int n = n0 + lane;
    int gp = b * 4096 + n;
    const float* src = Fsim + (size_t)b * 64 * 4096 + n;
    int tile = n >> 7, row = n & 127;
    unsigned short* dst = gA + (size_t)(b * NT + tile) * 8192 + row * 8;

    float racc = 0.f;
    #pragma unroll
    for (int q = 0; q < 2; ++q) {
        int chunk = wave * 2 + q;
        unsigned us[8];
        #pragma unroll
        for (int j = 0; j < 8; ++j) {
            float f = src[(size_t)(chunk * 8 + j) * 4096];
            unsigned u = __float_as_uint(f);
            u += 0x7fffu + ((u >> 16) & 1u);    // RNE to bf16
            us[j] = u >> 16;
            float fb = __uint_as_float(us[j] << 16);
            racc = fmaf(fb, fb, racc);
        }
        uint4 pk;
        pk.x = us[0] | (us[1] << 16);
        pk.y = us[2] | (us[3] << 16);
        pk.z = us[4] | (us[5] << 16);
        pk.w = us[6] | (us[7] << 16);
        *(uint4*)(dst + chunk * 1024) = pk;
    }
    sPart[wave][lane] = racc;
    __syncthreads();
    if (wave == 0) {
        gR[gp] = (sPart[0][lane] + sPart[1][lane]) +
                 (sPart[2][lane] + sPart[3][lane]);
        int tg = target[gp];
        gK[gp] = (tg >= 0) ? (float)tg : -(float)(n + 2);  // unique key
        gW[gp] = (float)tg;
    }
}

// ---------------- main: persistent, dbuf-staged 128x128 tile-pairs ----------------
// 512 threads = 8 waves/block; wave (wr,wc) owns rows [wr*64,+64) x cols [wc*32,+32).
__global__ __launch_bounds__(512, 4) void sgpn_main(
    const unsigned short* __restrict__ gA,
    const float* __restrict__ gR, const float* __restrict__ gK,
    const float* __restrict__ gW, float* __restrict__ gP)
{
    // [buf][A=0/B=1][8192] bf16 chunk-major tile images : 64 KB
    __shared__ __align__(16) unsigned short lT[2][2][8192];
    // [buf][row=0/col=1][R=0,K=1,W=2][128] : 6 KB
    __shared__ __align__(16) float sM[2][2][3][128];
    __shared__ float sRed[8];
    __shared__ float sMult[2];

    int tid = threadIdx.x;
    int lane = tid & 63;
    int wave = tid >> 6;               // 0..7
    int g = blockIdx.x;
    int np = (g < (NPAIR - 4 * NBLK)) ? 5 : 4;   // first 64 blocks take a 5th pair

    auto stage = [&](int P, int buf) {
        int b = P / TRI;
        int t = P - b * TRI;
        int tj = (int)((sqrtf(8.0f * (float)t + 1.0f) - 1.0f) * 0.5f);
        while ((tj + 1) * (tj + 2) / 2 <= t) ++tj;
        while (tj * (tj + 1) / 2 > t) --tj;
        int ti = t - tj * (tj + 1) / 2;

        const unsigned short* tA = gA + (size_t)(b * NT + ti) * 8192;
        const unsigned short* tB = gA + (size_t)(b * NT + tj) * 8192;
        #pragma unroll
        for (int it = 0; it < 2; ++it) {
            int e = it * 512 + tid;               // 16B chunk index (1024 per tile)
            async_load16(tA + e * 8, &lT[buf][0][e * 8]);
            async_load16(tB + e * 8, &lT[buf][1][e * 8]);
        }
        if (tid < 256) {
            int half = tid >> 7, p0 = tid & 127;
            int gp = b * 4096 + (half ? tj : ti) * 128 + p0;
            sM[buf][half][0][p0] = gR[gp];
            sM[buf][half][1][p0] = gK[gp];
            sM[buf][half][2][p0] = gW[gp];
        }
        if (tid == 0) sMult[buf] = (ti == tj) ? 1.f : 2.f;
    };

    int wr = wave >> 2, wc = wave & 3;           // row half / col quarter
    int quad = lane >> 4, lcol = lane & 15;

    float total = 0.f;
    stage(g, 0);

    for (int q = 0; q < np; ++q) {
        __syncthreads();                       // drains staging of buf q&1
        int buf = q & 1;
        if (q + 1 < np) stage(g + (q + 1) * NBLK, buf ^ 1);  // async prefetch

        // ---- MFMA on buf: wave computes 64x32 = acc[4][2] ----
        f32x4 acc[4][2];
        #pragma unroll
        for (int i = 0; i < 4; ++i)
            #pragma unroll
            for (int j = 0; j < 2; ++j)
                acc[i][j] = (f32x4)0.f;

        #pragma unroll
        for (int kb = 0; kb < 2; ++kb) {
            int chunk = kb * 4 + quad;
            bf16x8 fa[4], fb[2];
            #pragma unroll
            for (int i = 0; i < 4; ++i)
                fa[i] = *(const bf16x8*)&lT[buf][0][chunk * 1024 + (wr * 64 + i * 16 + lcol) * 8];
            #pragma unroll
            for (int j = 0; j < 2; ++j)
                fb[j] = *(const bf16x8*)&lT[buf][1][chunk * 1024 + (wc * 32 + j * 16 + lcol) * 8];
            #pragma unroll
            for (int i = 0; i < 4; ++i)
                #pragma unroll
                for (int j = 0; j < 2; ++j)
                    acc[i][j] = __builtin_amdgcn_mfma_f32_16x16x32_bf16(fa[i], fb[j], acc[i][j], 0, 0, 0);
        }

        // ---- epilogue: C/D layout col = lane&15, row = quad*4 + reg ----
        float rcv[2], kcv[2], wcv[2];
        #pragma unroll
        for (int j = 0; j < 2; ++j) {
            int cl = wc * 32 + j * 16 + lcol;
            rcv[j] = sM[buf][1][0][cl];
            kcv[j] = sM[buf][1][1][cl];
            wcv[j] = sM[buf][1][2][cl];
        }

        float sum = 0.f;
        #pragma unroll
        for (int i = 0; i < 4; ++i) {
            int rb = wr * 64 + i * 16 + quad * 4;          // 4-aligned
            f32x4 rr4 = *(const f32x4*)&sM[buf][0][0][rb];
            f32x4 kr4 = *(const f32x4*)&sM[buf][0][1][rb];
            f32x4 wr4 = *(const f32x4*)&sM[buf][0][2][rb];
            #pragma unroll
            for (int r = 0; r < 4; ++r) {
                float rrow = rr4[r], krow = kr4[r], wrow = wr4[r];
                float psum = 0.f;
                #pragma unroll
                for (int j = 0; j < 2; ++j) {
                    float gacc = acc[i][j][r];
                    float d0 = fmaf(-2.f, gacc, rrow + rcv[j]);
                    float D  = fmaxf(d0, 0.f);
                    float h  = fmaxf(fmaf(D, -2.f, 1.6f), 0.f);   // 2*max(0.8-D,0)
                    float v  = (krow == kcv[j]) ? D : h;
                    psum = fmaf(v, wcv[j], psum);
                }
                sum = fmaf(psum, wrow, sum);
            }
        }
        total = fmaf(sum, sMult[buf], total);
    }

    // reduce: wave shuffle -> LDS -> one store per block
    #pragma unroll
    for (int off = 32; off > 0; off >>= 1)
        total += __shfl_down(total, off, 64);
    if (lane == 0) sRed[wave] = total;
    __syncthreads();
    if (tid == 0)
        gP[g] = ((sRed[0] + sRed[1]) + (sRed[2] + sRed[3])) +
                ((sRed[4] + sRed[5]) + (sRed[6] + sRed[7]));
}

// ---------------- final: reduce 512 partials -> scalar mean ----------------
__global__ __launch_bounds__(256) void sgpn_reduce(
    const float* __restrict__ gP, float* __restrict__ out)
{
    __shared__ float sr[4];
    int tid = threadIdx.x;
    float s = gP[tid] + gP[tid + 256];
    #pragma unroll
    for (int off = 32; off > 0; off >>= 1)
        s += __shfl_down(s, off, 64);
    if ((tid & 63) == 0) sr[tid >> 6] = s;
    __syncthreads();
    if (tid == 0)
        out[0] = ((sr[0] + sr[1]) + (sr[2] + sr[3])) * SCALE;
}

extern "C" void kernel_launch(void* const* d_in, const int* in_sizes, int n_in,
                              void* d_out, int out_size, void* d_ws, size_t ws_size,
                              hipStream_t stream) {
    // d_in: [0]=l0_points (unused), [1]=Fsim fp32 [4,64,4096], [2]=target int32 [4,4096]
    const float* Fsim  = (const float*)d_in[1];
    const int* target  = (const int*)d_in[2];
    float* out = (float*)d_out;

    char* ws = (char*)d_ws;
    unsigned short* gA = (unsigned short*)ws;                 // 2 MB
    float* gR = (float*)(ws + (2u << 20));                    // 64 KB
    float* gK = (float*)(ws + (2u << 20) + (64u << 10));      // 64 KB
    float* gW = (float*)(ws + (2u << 20) + (128u << 10));     // 64 KB
    float* gP = (float*)(ws + (2u << 20) + (192u << 10));     // 2 KB

    sgpn_prep<<<256, 256, 0, stream>>>(Fsim, target, gA, gR, gK, gW);
    sgpn_main<<<NBLK, 512, 0, stream>>>(gA, gR, gK, gW, gP);
    sgpn_reduce<<<1, 256, 0, stream>>>(gP, out);
}